// Round 12
// baseline (9207.639 us; speedup 1.0000x reference)
//
#include <hip/hip_runtime.h>

// Problem constants (B,S,D=16,2048,256; K codebooks=8, CD=1024)
#define DD    256
#define KST   8
#define CDN   1024
#define NROWS 32768          // B*S
#define ROWS  64             // rows (tokens) per block (8 waves x 8 rows)
#define AST   64             // a_t row stride: 16B-aligned broadcasts, dense rows

// Transposed codebook, float2-granular:
// cbT[s][c2][j][2] = cb[s][j][2*c2 + 0..1], c2 = 0..127 (k-pair rows).
__device__ float cbT_buf[(size_t)KST * 128 * CDN * 2];   // 8 MB static

__device__ __forceinline__ bool better(float a, int ja, float b, int jb_) {
    return (a < b) || (a == b && ja < jb_);
}

// ---------------------------------------------------------------------------
// numpy AVX512 pairwise sum-of-squares over 256 values (bit-emulated).
template <typename F>
__device__ __forceinline__ float np_sumsq_256(F ld) {
    float Sv = 0.f;
#pragma unroll
    for (int blk = 0; blk < 2; ++blk) {
        const int o = blk * 128;
        float w[16];
#pragma unroll
        for (int l = 0; l < 16; ++l) {
            float v[8];
#pragma unroll
            for (int j = 0; j < 8; ++j) {
                float xv = ld(o + 16 * j + l);
                v[j] = __fmul_rn(xv, xv);
            }
            float a01 = __fadd_rn(v[0], v[1]);
            float a23 = __fadd_rn(v[2], v[3]);
            float a45 = __fadd_rn(v[4], v[5]);
            float a67 = __fadd_rn(v[6], v[7]);
            w[l] = __fadd_rn(__fadd_rn(a01, a23), __fadd_rn(a45, a67));
        }
        float t8[8];
#pragma unroll
        for (int l = 0; l < 8; ++l) t8[l] = __fadd_rn(w[l], w[l + 8]);
        float t4[4];
#pragma unroll
        for (int l = 0; l < 4; ++l) t4[l] = __fadd_rn(t8[l], t8[l + 4]);
        float t2_0 = __fadd_rn(t4[0], t4[2]);
        float t2_1 = __fadd_rn(t4[1], t4[3]);
        float bs = __fadd_rn(t2_0, t2_1);
        Sv = (blk == 0) ? bs : __fadd_rn(Sv, bs);
    }
    return Sv;
}

// ---------------------------------------------------------------------------
__global__ __launch_bounds__(256) void norms_kernel(const float* __restrict__ cb,
                                                    float* __restrict__ n32) {
    int j = blockIdx.x * 256 + threadIdx.x;   // 0..8191
    const float* p = cb + (size_t)j * DD;
    n32[j] = np_sumsq_256([&](int i) { return p[i]; });
}

// ---------------------------------------------------------------------------
// One-time codebook transpose into cbT_buf (float2 granules).
__global__ __launch_bounds__(256) void tr_kernel(const float* __restrict__ cb) {
    int idx = blockIdx.x * 256 + threadIdx.x;  // 0 .. 1048575
    int j  = idx & 1023;
    int c2 = (idx >> 10) & 127;
    int s  = idx >> 17;
    float2 v = *(const float2*)(cb + ((size_t)(s * CDN + j) * DD) + c2 * 2);
    *(float2*)(cbT_buf + (size_t)idx * 2) = v;
}

// ---------------------------------------------------------------------------
// Fused RVQ — numpy-fp32 emulation; B shared via LDS with DENSE bank geometry.
// Round 11 confirmed the L2-redundancy theory (VALUBusy 58.8%, highest yet)
// but added a 32-way bank conflict (lane stride 64B on B-reads; 4.04e8
// conflicts = ~19% of wall) and VALU bloat from readlane transport.
// This round: (1) lane owns cw pairs {q*128 + cg*2, +1}: per (kp,q) one
// ds_read_b128 at 16B lane stride = contiguous 1KB wave-read (m134 dense
// pattern, conflict-free). Ownership permutation is argmin-invariant.
// (2) A back to wave-uniform broadcast b128 per k (round-7-proven; zero
// readlane) -> k-loop ~94% pure FMA. AST=64: aligned every k, dense rows.
// (3) staging reg-based, issue-early/write-late, double-buffered 32KB tiles.
// Exactness: per-(row,cw) dot = one FMA chain, k = t*16+kp*2+kk ascending;
// same score compose + lexicographic argmin -> outputs bit-identical.
__global__ __launch_bounds__(512, 2) void rvq_kernel(const float* __restrict__ x,
                                                     const float* __restrict__ cbs,
                                                     const float* __restrict__ n32,
                                                     float* __restrict__ out) {
    __shared__ __align__(16) float a_t[DD][AST];       // 65536 B residual^T
    __shared__ __align__(16) float Bl[2][8][512][2];   // 65536 B dbuf B tiles
    __shared__ float rowS[ROWS];
    __shared__ float bestS[ROWS];
    __shared__ int   bestI[ROWS];
    __shared__ float wred[8];

    const int tid  = threadIdx.x;
    const int base = blockIdx.x * ROWS;
    const int cg   = tid & 63;            // lane
    const int ty   = tid >> 6;            // wave id = row-group (8 rows), 0..7
    const int row0 = ty * 8;
    const int urow = tid & 63;            // update row
    const int ug   = tid >> 6;            // owned 32-dim segment

    for (int i = tid; i < ROWS * DD / 4; i += 512) {
        int row = i >> 6;
        int dq  = i & 63;
        float4 v = ((const float4*)(x + (size_t)(base + row) * DD))[dq];
        int d = dq * 4;
        a_t[d + 0][row] = v.x; a_t[d + 1][row] = v.y;
        a_t[d + 2][row] = v.z; a_t[d + 3][row] = v.w;
    }

    float loss_acc = 0.f;

    for (int s = 0; s < KST; ++s) {
        const float* cb  = cbs + (size_t)s * CDN * DD;
        const float* nr  = n32 + s * CDN;
        const float* cts = cbT_buf + ((size_t)s << 18);
        __syncthreads();                  // (A) a_t stable; prev bestI reads done

        if (cg < 8) {                     // wave-local rows: sumsq + best init
            int row = row0 + cg;
            rowS[row] = np_sumsq_256([&](int i) { return a_t[i][row]; });
            bestS[row] = 3.4e38f;
            bestI[row] = 0x7ffffff;
        }

        for (int h = 0; h < 2; ++h) {
            __syncthreads();              // Bl fully free (prev h/stage done)

            float4 stg[4];
            // prologue: stage tile 0 -> buf 0 (tile = 8 kp x 512 cw = 32KB)
#pragma unroll
            for (int i = 0; i < 4; ++i) {
                int fidx = tid + i * 512;             // float4 slot in tile
                int kp = fidx >> 8, cwp = fidx & 255; // cw pair = 2*cwp
                stg[i] = *(const float4*)(cts +
                    ((size_t)kp * 1024 + h * 512 + 2 * cwp) * 2);
            }
#pragma unroll
            for (int i = 0; i < 4; ++i)
                ((float4*)&Bl[0][0][0][0])[tid + i * 512] = stg[i];

            float acc[8][8];              // [slot][r], slot = q*2+d
#pragma unroll
            for (int sl = 0; sl < 8; ++sl)
#pragma unroll
                for (int r = 0; r < 8; ++r) acc[sl][r] = 0.f;

#pragma unroll 1
            for (int t = 0; t < 16; ++t) {
                const int cur = t & 1;
                __syncthreads();          // Bl[cur] staged+visible; Bl[cur^1] free
                if (t < 15) {             // issue next tile's loads early
#pragma unroll
                    for (int i = 0; i < 4; ++i) {
                        int fidx = tid + i * 512;
                        int kp = fidx >> 8, cwp = fidx & 255;
                        stg[i] = *(const float4*)(cts +
                            ((size_t)((t + 1) * 8 + kp) * 1024 + h * 512 + 2 * cwp) * 2);
                    }
                }
                // compute tile t: per kp (2 k's): A = 4 broadcast b128,
                // B = 4 dense b128 (16B lane stride), 128 FMAs
#pragma unroll
                for (int kp = 0; kp < 8; ++kp) {
                    const int k0 = t * 16 + kp * 2;
                    float4 a00 = *(const float4*)&a_t[k0][row0];
                    float4 a01 = *(const float4*)&a_t[k0][row0 + 4];
                    float4 a10 = *(const float4*)&a_t[k0 + 1][row0];
                    float4 a11 = *(const float4*)&a_t[k0 + 1][row0 + 4];
                    float ar0[8] = {a00.x, a00.y, a00.z, a00.w,
                                    a01.x, a01.y, a01.z, a01.w};
                    float ar1[8] = {a10.x, a10.y, a10.z, a10.w,
                                    a11.x, a11.y, a11.z, a11.w};
                    float4 bq[4];
#pragma unroll
                    for (int q = 0; q < 4; ++q)
                        bq[q] = *(const float4*)&Bl[cur][kp][q * 128 + cg * 2][0];
                    // kk = 0 (k = k0): cw values .x (d=0) / .z (d=1)
#pragma unroll
                    for (int q = 0; q < 4; ++q) {
#pragma unroll
                        for (int r = 0; r < 8; ++r) {
                            acc[q * 2 + 0][r] = __builtin_fmaf(bq[q].x, ar0[r], acc[q * 2 + 0][r]);
                            acc[q * 2 + 1][r] = __builtin_fmaf(bq[q].z, ar0[r], acc[q * 2 + 1][r]);
                        }
                    }
                    // kk = 1 (k = k0+1): cw values .y / .w
#pragma unroll
                    for (int q = 0; q < 4; ++q) {
#pragma unroll
                        for (int r = 0; r < 8; ++r) {
                            acc[q * 2 + 0][r] = __builtin_fmaf(bq[q].y, ar1[r], acc[q * 2 + 0][r]);
                            acc[q * 2 + 1][r] = __builtin_fmaf(bq[q].w, ar1[r], acc[q * 2 + 1][r]);
                        }
                    }
                }
                if (t < 15) {             // write-late: loads covered by compute
#pragma unroll
                    for (int i = 0; i < 4; ++i)
                        ((float4*)&Bl[cur ^ 1][0][0][0])[tid + i * 512] = stg[i];
                }
            }

            // np-composed score + per-row 64-lane argmin butterfly
            float nrv[8];
#pragma unroll
            for (int q = 0; q < 4; ++q) {
                float2 nn = *(const float2*)(nr + h * 512 + q * 128 + cg * 2);
                nrv[q * 2 + 0] = nn.x;
                nrv[q * 2 + 1] = nn.y;
            }
#pragma unroll
            for (int r = 0; r < 8; ++r) {
                int row = row0 + r;
                float Sr = rowS[row];
                float t1 = 3.4e38f; int u1 = 0x7ffffff;
#pragma unroll
                for (int sl = 0; sl < 8; ++sl) {
                    int j = h * 512 + (sl >> 1) * 128 + cg * 2 + (sl & 1);
                    float m2 = __fmul_rn(2.f, acc[sl][r]);
                    float sc2 = __fadd_rn(__fsub_rn(Sr, m2), nrv[sl]);
                    if (better(sc2, j, t1, u1)) { t1 = sc2; u1 = j; }
                }
#pragma unroll
                for (int off = 32; off >= 1; off >>= 1) {
                    float ob = __shfl_xor(t1, off, 64);
                    int   oj = __shfl_xor(u1, off, 64);
                    if (better(ob, oj, t1, u1)) { t1 = ob; u1 = oj; }
                }
                if (cg == r) {            // wave owns the row: no merge
                    if (better(t1, u1, bestS[row], bestI[row])) {
                        bestS[row] = t1; bestI[row] = u1;
                    }
                }
            }
        }

        if (cg < 8) {                     // index output, wave-local rows
            int row = row0 + cg;
            out[2 + (size_t)(base + row) * KST + s] = (float)bestI[row];
        }
        __syncthreads();                  // (C) bestI final for all rows

        // residual update + loss (elementwise fp32)
        {
            int bi = bestI[urow];
            const float4* cp = (const float4*)(cb + (size_t)bi * DD + ug * 32);
#pragma unroll
            for (int dq = 0; dq < 8; ++dq) {
                float4 v = cp[dq];
                int d = ug * 32 + dq * 4;
                float e0 = __fsub_rn(a_t[d + 0][urow], v.x); a_t[d + 0][urow] = e0;
                float e1 = __fsub_rn(a_t[d + 1][urow], v.y); a_t[d + 1][urow] = e1;
                float e2 = __fsub_rn(a_t[d + 2][urow], v.z); a_t[d + 2][urow] = e2;
                float e3 = __fsub_rn(a_t[d + 3][urow], v.w); a_t[d + 3][urow] = e3;
                loss_acc += e0 * e0 + e1 * e1 + e2 * e2 + e3 * e3;
            }
        }
    }
    __syncthreads();                      // (E) a_t final

    // ---- outputs ---- (indices already written per stage)
    float* q = out + 2 + (size_t)NROWS * KST;
    for (int i = tid; i < ROWS * DD / 4; i += 512) {
        int row = i >> 6, dq = i & 63, d = dq * 4;
        float4 xv = ((const float4*)(x + (size_t)(base + row) * DD))[dq];
        float4 o;
        o.x = xv.x - a_t[d + 0][row];
        o.y = xv.y - a_t[d + 1][row];
        o.z = xv.z - a_t[d + 2][row];
        o.w = xv.w - a_t[d + 3][row];
        ((float4*)(q + (size_t)(base + row) * DD))[dq] = o;
    }
#pragma unroll
    for (int off = 32; off >= 1; off >>= 1) loss_acc += __shfl_down(loss_acc, off, 64);
    if ((tid & 63) == 0) wred[tid >> 6] = loss_acc;
    __syncthreads();
    if (tid == 0) {
        float t = ((wred[0] + wred[1]) + (wred[2] + wred[3]))
                + ((wred[4] + wred[5]) + (wred[6] + wred[7]));
        t *= (1.f / ((float)NROWS * (float)DD));
        atomicAdd(out + 0, t);
        atomicAdd(out + 1, t);
    }
}

// ---------------------------------------------------------------------------
extern "C" void kernel_launch(void* const* d_in, const int* in_sizes, int n_in,
                              void* d_out, int out_size, void* d_ws, size_t ws_size,
                              hipStream_t stream) {
    const float* x   = (const float*)d_in[0];   // [16,2048,256] fp32
    const float* cbs = (const float*)d_in[1];   // [8,1024,256] fp32
    float* out = (float*)d_out;
    float* n32 = (float*)d_ws;                  // 8192 floats

    hipMemsetAsync(d_out, 0, 2 * sizeof(float), stream);
    tr_kernel<<<4096, 256, 0, stream>>>(cbs);
    norms_kernel<<<32, 256, 0, stream>>>(cbs, n32);
    rvq_kernel<<<NROWS / ROWS, 512, 0, stream>>>(x, cbs, n32, out);
}

// Round 13
// 2101.603 us; speedup vs baseline: 4.3812x; 4.3812x over previous
//
#include <hip/hip_runtime.h>

// Problem constants (B,S,D=16,2048,256; K codebooks=8, CD=1024)
#define DD    256
#define KST   8
#define CDN   1024
#define NROWS 32768          // B*S
#define ROWS  64             // rows (tokens) per block (8 waves x 8 rows)
#define AST   64             // a_t row stride: 16B-aligned broadcasts, dense rows

// Transposed codebook, float2-granular:
// cbT[s][c2][j][2] = cb[s][j][2*c2 + 0..1], c2 = 0..127 (k-pair rows).
__device__ float cbT_buf[(size_t)KST * 128 * CDN * 2];   // 8 MB static

__device__ __forceinline__ bool better(float a, int ja, float b, int jb_) {
    return (a < b) || (a == b && ja < jb_);
}

// ---------------------------------------------------------------------------
// numpy AVX512 pairwise sum-of-squares over 256 values (bit-emulated).
template <typename F>
__device__ __forceinline__ float np_sumsq_256(F ld) {
    float Sv = 0.f;
#pragma unroll
    for (int blk = 0; blk < 2; ++blk) {
        const int o = blk * 128;
        float w[16];
#pragma unroll
        for (int l = 0; l < 16; ++l) {
            float v[8];
#pragma unroll
            for (int j = 0; j < 8; ++j) {
                float xv = ld(o + 16 * j + l);
                v[j] = __fmul_rn(xv, xv);
            }
            float a01 = __fadd_rn(v[0], v[1]);
            float a23 = __fadd_rn(v[2], v[3]);
            float a45 = __fadd_rn(v[4], v[5]);
            float a67 = __fadd_rn(v[6], v[7]);
            w[l] = __fadd_rn(__fadd_rn(a01, a23), __fadd_rn(a45, a67));
        }
        float t8[8];
#pragma unroll
        for (int l = 0; l < 8; ++l) t8[l] = __fadd_rn(w[l], w[l + 8]);
        float t4[4];
#pragma unroll
        for (int l = 0; l < 4; ++l) t4[l] = __fadd_rn(t8[l], t8[l + 4]);
        float t2_0 = __fadd_rn(t4[0], t4[2]);
        float t2_1 = __fadd_rn(t4[1], t4[3]);
        float bs = __fadd_rn(t2_0, t2_1);
        Sv = (blk == 0) ? bs : __fadd_rn(Sv, bs);
    }
    return Sv;
}

// ---------------------------------------------------------------------------
__global__ __launch_bounds__(256) void norms_kernel(const float* __restrict__ cb,
                                                    float* __restrict__ n32) {
    int j = blockIdx.x * 256 + threadIdx.x;   // 0..8191
    const float* p = cb + (size_t)j * DD;
    n32[j] = np_sumsq_256([&](int i) { return p[i]; });
}

// ---------------------------------------------------------------------------
// One-time codebook transpose into cbT_buf (float2 granules).
__global__ __launch_bounds__(256) void tr_kernel(const float* __restrict__ cb) {
    int idx = blockIdx.x * 256 + threadIdx.x;  // 0 .. 1048575
    int j  = idx & 1023;
    int c2 = (idx >> 10) & 127;
    int s  = idx >> 17;
    float2 v = *(const float2*)(cb + ((size_t)(s * CDN + j) * DD) + c2 * 2);
    *(float2*)(cbT_buf + (size_t)idx * 2) = v;
}

// ---------------------------------------------------------------------------
// Fused RVQ — numpy-fp32 emulation; B shared via LDS (dense banks) with
// global_load_lds staging (zero staging VGPRs).
// Round 11 proved the L2-redundancy theory (VALUBusy 58.8% after the 8x cut);
// round 12 proved the dense B-read geometry but spilled at the (512,2) 128-reg
// cap (stg16 + bq16 + ar16 + acc64 + addr ~= 140): WRITE_SIZE 24.5 GB.
// This round removes both register blocks:
//  * staging = __builtin_amdgcn_global_load_lds width 16 (DMA, no VGPR
//    roundtrip, no ds_write); issue after barrier, auto-drained by the
//    vmcnt(0) hipcc emits before the next s_barrier = exactly when needed.
//    LDS dest linear in fidx (wave-uniform base + lane*16); per-lane global
//    address carries the kp/cwp decomposition.
//  * per-q immediate B consumption: one float4 b live (4 regs), 32 FMAs
//    (k0 via .x/.z then k0+1 via .y/.w -> per-accumulator k still ascending).
// Budget: acc64 + ar16 + b4 + addr ~15 ~= 100 <= 128 -> no spill.
// Exactness: per-(row,cw) dot = one FMA chain, k = t*16+kp*2+kk ascending;
// same score compose + lexicographic argmin -> outputs bit-identical to
// round 12 (which passed).
__global__ __launch_bounds__(512, 2) void rvq_kernel(const float* __restrict__ x,
                                                     const float* __restrict__ cbs,
                                                     const float* __restrict__ n32,
                                                     float* __restrict__ out) {
    __shared__ __align__(16) float a_t[DD][AST];       // 65536 B residual^T
    __shared__ __align__(16) float Bl[2][8][512][2];   // 65536 B dbuf B tiles
    __shared__ float rowS[ROWS];
    __shared__ float bestS[ROWS];
    __shared__ int   bestI[ROWS];
    __shared__ float wred[8];

    const int tid  = threadIdx.x;
    const int base = blockIdx.x * ROWS;
    const int cg   = tid & 63;            // lane
    const int ty   = tid >> 6;            // wave id = row-group (8 rows), 0..7
    const int row0 = ty * 8;
    const int urow = tid & 63;            // update row
    const int ug   = tid >> 6;            // owned 32-dim segment

    for (int i = tid; i < ROWS * DD / 4; i += 512) {
        int row = i >> 6;
        int dq  = i & 63;
        float4 v = ((const float4*)(x + (size_t)(base + row) * DD))[dq];
        int d = dq * 4;
        a_t[d + 0][row] = v.x; a_t[d + 1][row] = v.y;
        a_t[d + 2][row] = v.z; a_t[d + 3][row] = v.w;
    }

    float loss_acc = 0.f;

    for (int s = 0; s < KST; ++s) {
        const float* cb  = cbs + (size_t)s * CDN * DD;
        const float* nr  = n32 + s * CDN;
        const float* cts = cbT_buf + ((size_t)s << 18);
        __syncthreads();                  // (A) a_t stable; prev bestI reads done

        if (cg < 8) {                     // wave-local rows: sumsq + best init
            int row = row0 + cg;
            rowS[row] = np_sumsq_256([&](int i) { return a_t[i][row]; });
            bestS[row] = 3.4e38f;
            bestI[row] = 0x7ffffff;
        }

        for (int h = 0; h < 2; ++h) {
            __syncthreads();              // Bl fully free (prev h/stage done)

            // async-stage one 32KB tile (8 kp x 512 cw) into Bl[buf]:
            // 4 global_load_lds per thread; LDS dest = wave base + lane*16,
            // global src per-lane. Completion guaranteed by the vmcnt(0)
            // drain hipcc emits before the next __syncthreads.
            auto STAGE = [&](int t, int buf) {
#pragma unroll
                for (int i = 0; i < 4; ++i) {
                    int fidx = tid + i * 512;             // float4 slot in tile
                    int kp = fidx >> 8, cwp = fidx & 255; // cw pair = 2*cwp
                    const float* g = cts + (size_t)(t * 8 + kp) * 2048
                                         + h * 1024 + cwp * 4;
                    char* l = (char*)(&Bl[buf][0][0][0]) + ty * 1024 + i * 8192;
                    __builtin_amdgcn_global_load_lds(
                        (const __attribute__((address_space(1))) void*)g,
                        (__attribute__((address_space(3))) void*)l, 16, 0, 0);
                }
            };

            STAGE(0, 0);                  // prologue: tile 0 -> buf 0

            float acc[8][8];              // [slot][r], slot = q*2+d
#pragma unroll
            for (int sl = 0; sl < 8; ++sl)
#pragma unroll
                for (int r = 0; r < 8; ++r) acc[sl][r] = 0.f;

#pragma unroll 1
            for (int t = 0; t < 16; ++t) {
                const int cur = t & 1;
                __syncthreads();          // vmcnt drained: Bl[cur] ready;
                                          // Bl[cur^1] reads (tile t-1) done
                if (t < 15) STAGE(t + 1, cur ^ 1);   // async next tile

                // compute tile t: per kp: A = 4 broadcast b128;
                // per q: 1 dense b128 (16B lane stride) + 32 FMAs
#pragma unroll
                for (int kp = 0; kp < 8; ++kp) {
                    const int k0 = t * 16 + kp * 2;
                    float4 a00 = *(const float4*)&a_t[k0][row0];
                    float4 a01 = *(const float4*)&a_t[k0][row0 + 4];
                    float4 a10 = *(const float4*)&a_t[k0 + 1][row0];
                    float4 a11 = *(const float4*)&a_t[k0 + 1][row0 + 4];
                    float ar0[8] = {a00.x, a00.y, a00.z, a00.w,
                                    a01.x, a01.y, a01.z, a01.w};
                    float ar1[8] = {a10.x, a10.y, a10.z, a10.w,
                                    a11.x, a11.y, a11.z, a11.w};
#pragma unroll
                    for (int q = 0; q < 4; ++q) {
                        float4 b = *(const float4*)&Bl[cur][kp][q * 128 + cg * 2][0];
                        // k = k0: cw 2j (.x) and 2j+1 (.z)
#pragma unroll
                        for (int r = 0; r < 8; ++r) {
                            acc[q * 2 + 0][r] = __builtin_fmaf(b.x, ar0[r], acc[q * 2 + 0][r]);
                            acc[q * 2 + 1][r] = __builtin_fmaf(b.z, ar0[r], acc[q * 2 + 1][r]);
                        }
                        // k = k0+1: .y / .w
#pragma unroll
                        for (int r = 0; r < 8; ++r) {
                            acc[q * 2 + 0][r] = __builtin_fmaf(b.y, ar1[r], acc[q * 2 + 0][r]);
                            acc[q * 2 + 1][r] = __builtin_fmaf(b.w, ar1[r], acc[q * 2 + 1][r]);
                        }
                    }
                }
            }

            // np-composed score + per-row 64-lane argmin butterfly
            float nrv[8];
#pragma unroll
            for (int q = 0; q < 4; ++q) {
                float2 nn = *(const float2*)(nr + h * 512 + q * 128 + cg * 2);
                nrv[q * 2 + 0] = nn.x;
                nrv[q * 2 + 1] = nn.y;
            }
#pragma unroll
            for (int r = 0; r < 8; ++r) {
                int row = row0 + r;
                float Sr = rowS[row];
                float t1 = 3.4e38f; int u1 = 0x7ffffff;
#pragma unroll
                for (int sl = 0; sl < 8; ++sl) {
                    int j = h * 512 + (sl >> 1) * 128 + cg * 2 + (sl & 1);
                    float m2 = __fmul_rn(2.f, acc[sl][r]);
                    float sc2 = __fadd_rn(__fsub_rn(Sr, m2), nrv[sl]);
                    if (better(sc2, j, t1, u1)) { t1 = sc2; u1 = j; }
                }
#pragma unroll
                for (int off = 32; off >= 1; off >>= 1) {
                    float ob = __shfl_xor(t1, off, 64);
                    int   oj = __shfl_xor(u1, off, 64);
                    if (better(ob, oj, t1, u1)) { t1 = ob; u1 = oj; }
                }
                if (cg == r) {            // wave owns the row: no merge
                    if (better(t1, u1, bestS[row], bestI[row])) {
                        bestS[row] = t1; bestI[row] = u1;
                    }
                }
            }
        }

        if (cg < 8) {                     // index output, wave-local rows
            int row = row0 + cg;
            out[2 + (size_t)(base + row) * KST + s] = (float)bestI[row];
        }
        __syncthreads();                  // (C) bestI final for all rows

        // residual update + loss (elementwise fp32; dense stride-1 banks)
        {
            int bi = bestI[urow];
            const float4* cp = (const float4*)(cb + (size_t)bi * DD + ug * 32);
#pragma unroll
            for (int dq = 0; dq < 8; ++dq) {
                float4 v = cp[dq];
                int d = ug * 32 + dq * 4;
                float e0 = __fsub_rn(a_t[d + 0][urow], v.x); a_t[d + 0][urow] = e0;
                float e1 = __fsub_rn(a_t[d + 1][urow], v.y); a_t[d + 1][urow] = e1;
                float e2 = __fsub_rn(a_t[d + 2][urow], v.z); a_t[d + 2][urow] = e2;
                float e3 = __fsub_rn(a_t[d + 3][urow], v.w); a_t[d + 3][urow] = e3;
                loss_acc += e0 * e0 + e1 * e1 + e2 * e2 + e3 * e3;
            }
        }
    }
    __syncthreads();                      // (E) a_t final

    // ---- outputs ---- (indices already written per stage)
    float* q = out + 2 + (size_t)NROWS * KST;
    for (int i = tid; i < ROWS * DD / 4; i += 512) {
        int row = i >> 6, dq = i & 63, d = dq * 4;
        float4 xv = ((const float4*)(x + (size_t)(base + row) * DD))[dq];
        float4 o;
        o.x = xv.x - a_t[d + 0][row];
        o.y = xv.y - a_t[d + 1][row];
        o.z = xv.z - a_t[d + 2][row];
        o.w = xv.w - a_t[d + 3][row];
        ((float4*)(q + (size_t)(base + row) * DD))[dq] = o;
    }
#pragma unroll
    for (int off = 32; off >= 1; off >>= 1) loss_acc += __shfl_down(loss_acc, off, 64);
    if ((tid & 63) == 0) wred[tid >> 6] = loss_acc;
    __syncthreads();
    if (tid == 0) {
        float t = ((wred[0] + wred[1]) + (wred[2] + wred[3]))
                + ((wred[4] + wred[5]) + (wred[6] + wred[7]));
        t *= (1.f / ((float)NROWS * (float)DD));
        atomicAdd(out + 0, t);
        atomicAdd(out + 1, t);
    }
}

// ---------------------------------------------------------------------------
extern "C" void kernel_launch(void* const* d_in, const int* in_sizes, int n_in,
                              void* d_out, int out_size, void* d_ws, size_t ws_size,
                              hipStream_t stream) {
    const float* x   = (const float*)d_in[0];   // [16,2048,256] fp32
    const float* cbs = (const float*)d_in[1];   // [8,1024,256] fp32
    float* out = (float*)d_out;
    float* n32 = (float*)d_ws;                  // 8192 floats

    hipMemsetAsync(d_out, 0, 2 * sizeof(float), stream);
    tr_kernel<<<4096, 256, 0, stream>>>(cbs);
    norms_kernel<<<32, 256, 0, stream>>>(cbs, n32);
    rvq_kernel<<<NROWS / ROWS, 512, 0, stream>>>(x, cbs, n32, out);
}